// Round 2
// baseline (995.715 us; speedup 1.0000x reference)
//
#include <hip/hip_runtime.h>
#include <hip/hip_bf16.h>

typedef unsigned short ushort_t;
typedef unsigned int uint_t;
typedef unsigned long long u64_t;

typedef __attribute__((ext_vector_type(8))) short bf16x8;   // 8 bf16 (4 VGPRs)
typedef __attribute__((ext_vector_type(4))) float floatx4;  // MFMA C/D

#define DI __device__ __forceinline__

// NOTE: record packing uses 17 bits for src -> requires N < 131072. (N=100000)
// Final edge record (4B): bits 0..16 = src, bits 17..31 = bf16(|w|) sans sign
// (w >= 0 so bf16 sign bit is always 0; decode = (rec>>1) & 0xFFFF0000).
#define NPB 128          // nodes per bucket
#define NBMAX 1024       // max buckets (N <= 131072)
#define CH 8             // src chunks (kept in sort key; harmless ordering)

// bf16 bits -> f32
DI float b2f(uint_t lo16) {
    union { uint_t u; float f; } v; v.u = lo16 << 16; return v.f;
}
// f32 -> bf16 bits, round-to-nearest-even
DI ushort_t f2b(float f) {
    union { float f; uint_t u; } v; v.f = f;
    uint_t u = v.u;
    uint_t r = (u + 0x7fffu + ((u >> 16) & 1u)) >> 16;
    return (ushort_t)r;
}
// decode 15-bit packed |w| from a 4B edge record
DI float wdec(uint_t rec) {
    union { uint_t u; float f; } v;
    v.u = (rec >> 1) & 0xFFFF0000u;
    return v.f;
}

// fma 8 bf16 feats (packed in uint4) into acc[8]
DI void fma8(float* a, uint4 v, float nm) {
    a[0] += nm * b2f(v.x & 0xffffu); a[1] += nm * b2f(v.x >> 16);
    a[2] += nm * b2f(v.y & 0xffffu); a[3] += nm * b2f(v.y >> 16);
    a[4] += nm * b2f(v.z & 0xffffu); a[5] += nm * b2f(v.z >> 16);
    a[6] += nm * b2f(v.w & 0xffffu); a[7] += nm * b2f(v.w >> 16);
}
// fma 4 bf16 feats (packed in uint2) into acc[4]
DI void fma4(float* a, uint2 v, float nm) {
    a[0] += nm * b2f(v.x & 0xffffu); a[1] += nm * b2f(v.x >> 16);
    a[2] += nm * b2f(v.y & 0xffffu); a[3] += nm * b2f(v.y >> 16);
}

// ---------------- P1: bucket histogram (LDS-binned) --------------------------
// Persists this block's per-bucket counts row to hist_g for deterministic scatter.
__global__ __launch_bounds__(1024) void gcn_bhist(
    const int* __restrict__ ei, int* __restrict__ bkt_cnt,
    int* __restrict__ hist_g, int E, int NB)
{
    __shared__ int hist[NBMAX];
    int t = threadIdx.x;
    for (int b = t; b < NB; b += 1024) hist[b] = 0;
    __syncthreads();
    int base = blockIdx.x * 32768;
    int lim = min(32768, E - base);
    for (int i = t; i < lim; i += 1024) {
        int d = ei[(size_t)E + base + i];
        atomicAdd(&hist[d >> 7], 1);
    }
    __syncthreads();
    int* row = hist_g + (size_t)blockIdx.x * NBMAX;
    for (int b = t; b < NB; b += 1024) {
        int c = hist[b];
        row[b] = c;
        if (c) atomicAdd(&bkt_cnt[b], c);
    }
}

// ---------------- P2: scan bucket counts -> bases ----------------------------
__global__ __launch_bounds__(256) void gcn_bscan(
    const int* __restrict__ bkt_cnt, int* __restrict__ bkt_base,
    int* __restrict__ rp, int NB, int N, int E)
{
    __shared__ int lds[256];
    int t = threadIdx.x;
    int v[4]; int s = 0;
    #pragma unroll
    for (int j = 0; j < 4; j++) {
        int b = t * 4 + j;
        v[j] = (b < NB) ? bkt_cnt[b] : 0;
        s += v[j];
    }
    lds[t] = s;
    __syncthreads();
    #pragma unroll
    for (int off = 1; off < 256; off <<= 1) {
        int y = (t >= off) ? lds[t - off] : 0;
        __syncthreads();
        lds[t] += y;
        __syncthreads();
    }
    int run = lds[t] - s;
    #pragma unroll
    for (int j = 0; j < 4; j++) {
        int b = t * 4 + j;
        if (b < NB) bkt_base[b] = run;
        run += v[j];
    }
    if (t == 255) { bkt_base[NB] = E; rp[N] = E; }
}

// ---------------- P2b: rebase per-block rows -> deterministic write bases ----
__global__ __launch_bounds__(256) void gcn_brebase(
    int* __restrict__ hist_g, const int* __restrict__ bkt_base, int NB, int nrows)
{
    int k = blockIdx.x * 256 + threadIdx.x;
    if (k >= NB) return;
    int run = bkt_base[k];
    for (int r = 0; r < nrows; r++) {
        int* p = hist_g + (size_t)r * NBMAX + k;
        int v = *p;
        *p = run;
        run += v;
    }
}

// ---------------- P3: scatter records into bucket regions (no global atomics) -
// record: x = src | (dst&127)<<17 ; y = |w| (f32 bits). Per-edge atomics are LDS.
__global__ __launch_bounds__(1024) void gcn_bscatter(
    const int* __restrict__ ei, const float* __restrict__ ew,
    const int* __restrict__ hist_g, uint2* __restrict__ stage, int E, int NB)
{
    __shared__ int cur[NBMAX];
    int t = threadIdx.x;
    const int* row = hist_g + (size_t)blockIdx.x * NBMAX;
    for (int b = t; b < NB; b += 1024) cur[b] = row[b];
    __syncthreads();
    int base = blockIdx.x * 32768;
    int lim = min(32768, E - base);
    for (int i = t; i < lim; i += 1024) {
        int e = base + i;
        int s = ei[e];
        int d = ei[(size_t)E + e];
        float w = fabsf(ew[e]);
        int pos = atomicAdd(&cur[d >> 7], 1);
        uint2 rec;
        rec.x = (uint_t)s | ((uint_t)(d & 127) << 17);
        rec.y = __float_as_uint(w);
        stage[pos] = rec;
    }
}

// ---------------- P4: per-bucket counting sort by (node, src-chunk) ----------
// Emits rp[n] (node boundaries; global-contiguous across buckets), dis, and the
// compact 4B edge records (src | bf16(|w|)<<17).
__global__ __launch_bounds__(256) void gcn_bsort(
    const uint2* __restrict__ stage, uint_t* __restrict__ edges,
    const int* __restrict__ bkt_base, int* __restrict__ rp,
    float* __restrict__ dis, int N)
{
    int b = blockIdx.x;
    int base = bkt_base[b], end = bkt_base[b + 1];
    int cnte = end - base;
    int n0 = b << 7;
    __shared__ int cnt[NPB * CH];     // 1024 bins
    __shared__ float wsum[NPB];
    __shared__ int scn[256];
    __shared__ int cur[NPB * CH];
    int t = threadIdx.x;
    for (int i = t; i < NPB * CH; i += 256) cnt[i] = 0;
    if (t < NPB) wsum[t] = 0.0f;
    __syncthreads();
    for (int i = t; i < cnte; i += 256) {
        uint2 r = stage[base + i];
        int dl = (r.x >> 17) & 127;
        int ch = (r.x & 0x1FFFF) >> 14;
        atomicAdd(&cnt[dl * CH + ch], 1);
        atomicAdd(&wsum[dl], __uint_as_float(r.y));
    }
    __syncthreads();
    int v0 = cnt[t * 4], v1 = cnt[t * 4 + 1], v2 = cnt[t * 4 + 2], v3 = cnt[t * 4 + 3];
    int s = v0 + v1 + v2 + v3;
    scn[t] = s;
    __syncthreads();
    #pragma unroll
    for (int off = 1; off < 256; off <<= 1) {
        int y = (t >= off) ? scn[t - off] : 0;
        __syncthreads();
        scn[t] += y;
        __syncthreads();
    }
    int e0 = scn[t] - s;
    int e1 = e0 + v0, e2 = e1 + v1, e3 = e2 + v2;
    cur[t * 4]     = base + e0;
    cur[t * 4 + 1] = base + e1;
    cur[t * 4 + 2] = base + e2;
    cur[t * 4 + 3] = base + e3;
    // node dl's start = prefix of bin dl*CH (CH=8 -> bin 8dl, thread 2dl, j=0)
    if ((t & 1) == 0) {
        int dl = t >> 1;
        int n = n0 + dl;
        if (n < N) {
            rp[n] = base + e0;
            dis[n] = rsqrtf(wsum[dl] + 1.0f);
        }
    }
    __syncthreads();
    for (int i = t; i < cnte; i += 256) {
        uint2 r = stage[base + i];
        int dl = (r.x >> 17) & 127;
        int ch = (r.x & 0x1FFFF) >> 14;
        int pos = atomicAdd(&cur[dl * CH + ch], 1);
        // compact 4B record: src (17b) | sign-stripped bf16(|w|) (15b)
        edges[pos] = (r.x & 0x1FFFFu) | ((uint_t)f2b(__uint_as_float(r.y)) << 17);
    }
}

// ---------------- weight transpose + bf16 convert (once per call, tiny) -------
__global__ __launch_bounds__(256) void gcn_wt(
    const float* __restrict__ W1, const float* __restrict__ W2,
    const float* __restrict__ W3,
    ushort_t* __restrict__ Wt1, ushort_t* __restrict__ Wt2,
    ushort_t* __restrict__ Wt3)
{
    int i = blockIdx.x * 256 + threadIdx.x;
    if (i < 96 * 128) {                       // layer 1: Wt1[96][128]
        int n = i / 128, k = i % 128;
        Wt1[i] = f2b(W1[k * 96 + n]);
    }
    if (i < 96 * 96) {                        // layer 2: Wt2[96][96]
        int n = i / 96, k = i % 96;
        Wt2[i] = f2b(W2[k * 96 + n]);
    }
    if (i < 32 * 96) {                        // layer 3: Wt3[32][96], pad rows 30,31
        int n = i / 96, k = i % 96;
        Wt3[i] = f2b((n < 30) ? W3[k * 30 + n] : 0.0f);
    }
}

// ---------------- MFMA GEMM: slice-major Y = dis[row] * (X[row,:] @ W) -------
// Output layout: Y[slice][node][SLICE_F] (bf16, dense). Per-XCD slice tables
// for the aggregation pass: slice s of layers 1/2 is 100000*24B = 2.4MB,
// L2-resident on one XCD.
template<int K, int FOUT, int NTR, int SLICE_F, bool XF32>
__global__ __launch_bounds__(256) void gcn_gemm_mfma(
    const void* __restrict__ Xv, const ushort_t* __restrict__ Wt,
    const float* __restrict__ dis, ushort_t* __restrict__ Y, int N)
{
    constexpr int KS = K + 8;
    constexpr int KT = K / 32;
    constexpr int NT = NTR / 16;
    __shared__ ushort_t xs[64 * KS];
    __shared__ ushort_t ws[NTR * KS];

    int t = threadIdx.x;
    int mbase = blockIdx.x * 64;

    {
        constexpr int TOT = NTR * (K / 8);
        const uint4* wg = (const uint4*)Wt;
        for (int i = t; i < TOT; i += 256) {
            int r = i / (K / 8), c8 = i % (K / 8);
            *(uint4*)(ws + r * KS + c8 * 8) = wg[i];
        }
    }
    if (XF32) {
        const float* X = (const float*)Xv;
        constexpr int TOT = 64 * (K / 4);
        for (int i = t; i < TOT; i += 256) {
            int row = i / (K / 4), c4 = i % (K / 4);
            int rg = mbase + row; if (rg >= N) rg = N - 1;
            float4 v = *(const float4*)(X + (size_t)rg * K + c4 * 4);
            uint2 pv;
            pv.x = (uint_t)f2b(v.x) | ((uint_t)f2b(v.y) << 16);
            pv.y = (uint_t)f2b(v.z) | ((uint_t)f2b(v.w) << 16);
            *(uint2*)(xs + row * KS + c4 * 4) = pv;
        }
    } else {
        const ushort_t* X = (const ushort_t*)Xv;
        constexpr int TOT = 64 * (K / 8);
        for (int i = t; i < TOT; i += 256) {
            int row = i / (K / 8), c8 = i % (K / 8);
            int rg = mbase + row; if (rg >= N) rg = N - 1;
            *(uint4*)(xs + row * KS + c8 * 8) = *(const uint4*)(X + (size_t)rg * K + c8 * 8);
        }
    }
    __syncthreads();

    int wave = t >> 6;
    int lane = t & 63;
    int l15 = lane & 15, quad = lane >> 4;

    bf16x8 af[KT];
    #pragma unroll
    for (int kt = 0; kt < KT; kt++)
        af[kt] = *(const bf16x8*)(xs + (wave * 16 + l15) * KS + kt * 32 + quad * 8);

    floatx4 acc[NT];
    #pragma unroll
    for (int nt = 0; nt < NT; nt++) acc[nt] = (floatx4){0.f, 0.f, 0.f, 0.f};

    #pragma unroll
    for (int nt = 0; nt < NT; nt++) {
        #pragma unroll
        for (int kt = 0; kt < KT; kt++) {
            bf16x8 bfr = *(const bf16x8*)(ws + (nt * 16 + l15) * KS + kt * 32 + quad * 8);
            acc[nt] = __builtin_amdgcn_mfma_f32_16x16x32_bf16(af[kt], bfr, acc[nt], 0, 0, 0);
        }
    }

    float dsc[4];
    #pragma unroll
    for (int r = 0; r < 4; r++) {
        int row = mbase + wave * 16 + quad * 4 + r;
        dsc[r] = (row < N) ? dis[row] : 0.0f;
    }
    #pragma unroll
    for (int nt = 0; nt < NT; nt++) {
        int col = nt * 16 + l15;
        int sl = col / SLICE_F, p = col % SLICE_F;
        #pragma unroll
        for (int r = 0; r < 4; r++) {
            int row = mbase + wave * 16 + quad * 4 + r;
            if (row < N) {
                float v = (col < FOUT) ? acc[nt][r] * dsc[r] : 0.0f;
                Y[((size_t)sl * N + row) * SLICE_F + p] = f2b(v);
            }
        }
    }
}

// ---------------- aggregation: XCD-aligned feature-slice partition ------------
// Node-parallel agg was at its compulsory-traffic floor: 2.44 table sweeps x
// 8 XCDs x 19.2MB ~= the measured 363MB FETCH. Instead: slice = blockIdx%8
// (round-robin block->XCD dispatch pins each slice to one XCD); each XCD's
// gather table is [N][12] bf16 = 2.4MB -> L2-resident. HBM cost is the 4B
// record stream re-read once per slice (nontemporal: don't evict the table).
// XWS = dis-scaled xw. H[n] = relu(b + dis[n]*(sum_e w*XWS[src] + XWS[n])).
__global__ __launch_bounds__(192) void gcn_agg96(
    const ushort_t* __restrict__ XWS, const int* __restrict__ rp,
    const uint_t* __restrict__ edges,
    const float* __restrict__ dis, const float* __restrict__ bias,
    ushort_t* __restrict__ H, int N)
{
    int slice = blockIdx.x & 7;            // -> XCD slice (bid%8 round-robin)
    int nb = blockIdx.x >> 3;
    int t = threadIdx.x;
    int n = nb * 64 + t / 3;               // 3 lanes per node (3 x uint2 = 24B)
    int sub = t % 3;
    if (n >= N) return;

    const uint2* xs = (const uint2*)XWS;   // slice row = 12 shorts = 3 uint2
    size_t sb = (size_t)slice * N;

    int beg = rp[n], end = rp[n + 1];
    float a[4] = {0.f, 0.f, 0.f, 0.f};

    int e = beg;
    for (; e + 8 <= end; e += 8) {
        uint_t r0 = __builtin_nontemporal_load(edges + e);
        uint_t r1 = __builtin_nontemporal_load(edges + e + 1);
        uint_t r2 = __builtin_nontemporal_load(edges + e + 2);
        uint_t r3 = __builtin_nontemporal_load(edges + e + 3);
        uint_t r4 = __builtin_nontemporal_load(edges + e + 4);
        uint_t r5 = __builtin_nontemporal_load(edges + e + 5);
        uint_t r6 = __builtin_nontemporal_load(edges + e + 6);
        uint_t r7 = __builtin_nontemporal_load(edges + e + 7);
        uint2 v0 = xs[(sb + (r0 & 0x1FFFFu)) * 3 + sub];
        uint2 v1 = xs[(sb + (r1 & 0x1FFFFu)) * 3 + sub];
        uint2 v2 = xs[(sb + (r2 & 0x1FFFFu)) * 3 + sub];
        uint2 v3 = xs[(sb + (r3 & 0x1FFFFu)) * 3 + sub];
        uint2 v4 = xs[(sb + (r4 & 0x1FFFFu)) * 3 + sub];
        uint2 v5 = xs[(sb + (r5 & 0x1FFFFu)) * 3 + sub];
        uint2 v6 = xs[(sb + (r6 & 0x1FFFFu)) * 3 + sub];
        uint2 v7 = xs[(sb + (r7 & 0x1FFFFu)) * 3 + sub];
        fma4(a, v0, wdec(r0));
        fma4(a, v1, wdec(r1));
        fma4(a, v2, wdec(r2));
        fma4(a, v3, wdec(r3));
        fma4(a, v4, wdec(r4));
        fma4(a, v5, wdec(r5));
        fma4(a, v6, wdec(r6));
        fma4(a, v7, wdec(r7));
    }
    for (; e + 4 <= end; e += 4) {
        uint_t r0 = __builtin_nontemporal_load(edges + e);
        uint_t r1 = __builtin_nontemporal_load(edges + e + 1);
        uint_t r2 = __builtin_nontemporal_load(edges + e + 2);
        uint_t r3 = __builtin_nontemporal_load(edges + e + 3);
        uint2 v0 = xs[(sb + (r0 & 0x1FFFFu)) * 3 + sub];
        uint2 v1 = xs[(sb + (r1 & 0x1FFFFu)) * 3 + sub];
        uint2 v2 = xs[(sb + (r2 & 0x1FFFFu)) * 3 + sub];
        uint2 v3 = xs[(sb + (r3 & 0x1FFFFu)) * 3 + sub];
        fma4(a, v0, wdec(r0));
        fma4(a, v1, wdec(r1));
        fma4(a, v2, wdec(r2));
        fma4(a, v3, wdec(r3));
    }
    for (; e < end; e++) {
        uint_t r0 = __builtin_nontemporal_load(edges + e);
        uint2 v0 = xs[(sb + (r0 & 0x1FFFFu)) * 3 + sub];
        fma4(a, v0, wdec(r0));
    }

    uint2 sv = xs[(sb + n) * 3 + sub];
    fma4(a, sv, 1.0f);                     // + XWS[n]
    float d = dis[n];
    int f0 = slice * 12 + sub * 4;
    uint_t oA = (uint_t)f2b(fmaxf(a[0] * d + bias[f0],     0.f))
              | ((uint_t)f2b(fmaxf(a[1] * d + bias[f0 + 1], 0.f)) << 16);
    uint_t oB = (uint_t)f2b(fmaxf(a[2] * d + bias[f0 + 2], 0.f))
              | ((uint_t)f2b(fmaxf(a[3] * d + bias[f0 + 3], 0.f)) << 16);
    uint2 ov = {oA, oB};
    *(uint2*)(H + (size_t)n * 96 + f0) = ov;   // byte off 192n+24s+8sub, 8B-aligned
}

// Layer 3: 4 slices x 8 feats (16B rows). slice = bid%4 -> resident on XCDs
// {s, s+4}, each caching the 1.6MB slice table. One lane per node.
__global__ __launch_bounds__(256) void gcn_agg32(
    const ushort_t* __restrict__ XWS, const int* __restrict__ rp,
    const uint_t* __restrict__ edges,
    const float* __restrict__ dis, const float* __restrict__ bias,
    ushort_t* __restrict__ H, int N)
{
    int slice = blockIdx.x & 3;
    int nb = blockIdx.x >> 2;
    int t = threadIdx.x;
    int n = nb * 256 + t;
    if (n >= N) return;

    const uint4* xs = (const uint4*)XWS;   // slice row = 8 shorts = 1 uint4
    size_t sb = (size_t)slice * N;

    int beg = rp[n], end = rp[n + 1];
    float a[8];
    #pragma unroll
    for (int j = 0; j < 8; j++) a[j] = 0.0f;

    int e = beg;
    for (; e + 8 <= end; e += 8) {
        uint_t r0 = __builtin_nontemporal_load(edges + e);
        uint_t r1 = __builtin_nontemporal_load(edges + e + 1);
        uint_t r2 = __builtin_nontemporal_load(edges + e + 2);
        uint_t r3 = __builtin_nontemporal_load(edges + e + 3);
        uint_t r4 = __builtin_nontemporal_load(edges + e + 4);
        uint_t r5 = __builtin_nontemporal_load(edges + e + 5);
        uint_t r6 = __builtin_nontemporal_load(edges + e + 6);
        uint_t r7 = __builtin_nontemporal_load(edges + e + 7);
        uint4 v0 = xs[sb + (r0 & 0x1FFFFu)];
        uint4 v1 = xs[sb + (r1 & 0x1FFFFu)];
        uint4 v2 = xs[sb + (r2 & 0x1FFFFu)];
        uint4 v3 = xs[sb + (r3 & 0x1FFFFu)];
        uint4 v4 = xs[sb + (r4 & 0x1FFFFu)];
        uint4 v5 = xs[sb + (r5 & 0x1FFFFu)];
        uint4 v6 = xs[sb + (r6 & 0x1FFFFu)];
        uint4 v7 = xs[sb + (r7 & 0x1FFFFu)];
        fma8(a, v0, wdec(r0));
        fma8(a, v1, wdec(r1));
        fma8(a, v2, wdec(r2));
        fma8(a, v3, wdec(r3));
        fma8(a, v4, wdec(r4));
        fma8(a, v5, wdec(r5));
        fma8(a, v6, wdec(r6));
        fma8(a, v7, wdec(r7));
    }
    for (; e + 4 <= end; e += 4) {
        uint_t r0 = __builtin_nontemporal_load(edges + e);
        uint_t r1 = __builtin_nontemporal_load(edges + e + 1);
        uint_t r2 = __builtin_nontemporal_load(edges + e + 2);
        uint_t r3 = __builtin_nontemporal_load(edges + e + 3);
        uint4 v0 = xs[sb + (r0 & 0x1FFFFu)];
        uint4 v1 = xs[sb + (r1 & 0x1FFFFu)];
        uint4 v2 = xs[sb + (r2 & 0x1FFFFu)];
        uint4 v3 = xs[sb + (r3 & 0x1FFFFu)];
        fma8(a, v0, wdec(r0));
        fma8(a, v1, wdec(r1));
        fma8(a, v2, wdec(r2));
        fma8(a, v3, wdec(r3));
    }
    for (; e < end; e++) {
        uint_t r0 = __builtin_nontemporal_load(edges + e);
        uint4 v0 = xs[sb + (r0 & 0x1FFFFu)];
        fma8(a, v0, wdec(r0));
    }

    uint4 sv = xs[sb + n];
    fma8(a, sv, 1.0f);                     // + XWS[n]
    float d = dis[n];
    int f0 = slice * 8;
    uint_t o[4];
    #pragma unroll
    for (int p = 0; p < 4; p++) {
        int fA = f0 + 2 * p, fB = f0 + 2 * p + 1;
        float rA = (fA < 30) ? fmaxf(a[2 * p]     * d + bias[fA], 0.f) : 0.f;
        float rB = (fB < 30) ? fmaxf(a[2 * p + 1] * d + bias[fB], 0.f) : 0.f;
        o[p] = (uint_t)f2b(rA) | ((uint_t)f2b(rB) << 16);
    }
    uint4 ov = {o[0], o[1], o[2], o[3]};
    *(uint4*)(H + (size_t)n * 32 + f0) = ov;   // byte off 64n+16s, 16B-aligned
}

// ---------------- mean-pool per graph + final linear + softmax ----------------
__global__ __launch_bounds__(256) void gcn_pool(
    const ushort_t* __restrict__ H, const int* __restrict__ batch,
    const float* __restrict__ Wf, const float* __restrict__ bf_,
    float* __restrict__ out, int N)
{
    __shared__ float pool[32];
    int g = blockIdx.x;
    int t = threadIdx.x;

    int lo = 0, hi = N;
    while (lo < hi) { int mid = (lo + hi) >> 1; if (batch[mid] < g) lo = mid + 1; else hi = mid; }
    int start = lo;
    lo = 0; hi = N;
    while (lo < hi) { int mid = (lo + hi) >> 1; if (batch[mid] < g + 1) lo = mid + 1; else hi = mid; }
    int end = lo;

    float acc[32];
    #pragma unroll
    for (int f = 0; f < 32; f++) acc[f] = 0.0f;
    for (int i = start + t; i < end; i += 256) {
        const uint2* hr = (const uint2*)H + (size_t)i * 8;
        #pragma unroll
        for (int q = 0; q < 8; q++) {
            uint2 v = hr[q];
            acc[4 * q + 0] += b2f(v.x & 0xffffu);
            acc[4 * q + 1] += b2f(v.x >> 16);
            acc[4 * q + 2] += b2f(v.y & 0xffffu);
            acc[4 * q + 3] += b2f(v.y >> 16);
        }
    }
    #pragma unroll
    for (int f = 0; f < 32; f++) {
        float v = acc[f];
        v += __shfl_down(v, 32, 64);
        v += __shfl_down(v, 16, 64);
        v += __shfl_down(v, 8, 64);
        v += __shfl_down(v, 4, 64);
        v += __shfl_down(v, 2, 64);
        v += __shfl_down(v, 1, 64);
        acc[f] = v;
    }
    if (t < 32) pool[t] = 0.0f;
    __syncthreads();
    if ((t & 63) == 0) {
        #pragma unroll
        for (int f = 0; f < 30; f++) atomicAdd(&pool[f], acc[f]);
    }
    __syncthreads();
    if (t == 0) {
        float inv = 1.0f / fmaxf((float)(end - start), 1.0f);
        float lg[10];
        #pragma unroll
        for (int j = 0; j < 10; j++) lg[j] = bf_[j];
        for (int f = 0; f < 30; f++) {
            float p = pool[f] * inv;
            #pragma unroll
            for (int j = 0; j < 10; j++) lg[j] += p * Wf[f * 10 + j];
        }
        float m = lg[0];
        #pragma unroll
        for (int j = 1; j < 10; j++) m = fmaxf(m, lg[j]);
        float s = 0.f;
        #pragma unroll
        for (int j = 0; j < 10; j++) { lg[j] = __expf(lg[j] - m); s += lg[j]; }
        float is = 1.0f / s;
        #pragma unroll
        for (int j = 0; j < 10; j++) out[g * 10 + j] = lg[j] * is;
    }
}

extern "C" void kernel_launch(void* const* d_in, const int* in_sizes, int n_in,
                              void* d_out, int out_size, void* d_ws, size_t ws_size,
                              hipStream_t stream) {
    (void)n_in; (void)out_size; (void)ws_size;
    const float* x   = (const float*)d_in[0];
    const int*   ei  = (const int*)d_in[1];
    const float* ew  = (const float*)d_in[2];
    const int*   bat = (const int*)d_in[3];
    const float* W1  = (const float*)d_in[4];
    const float* b1  = (const float*)d_in[5];
    const float* W2  = (const float*)d_in[6];
    const float* b2  = (const float*)d_in[7];
    const float* W3  = (const float*)d_in[8];
    const float* b3  = (const float*)d_in[9];
    const float* Wf  = (const float*)d_in[10];
    const float* bf_ = (const float*)d_in[11];
    float* out = (float*)d_out;

    const int N = in_sizes[3];       // 100000
    const int E = in_sizes[2];       // 3200000
    const int NB = (N + NPB - 1) / NPB;   // 782
    const int gB = (E + 32767) / 32768;   // 98

    char* wsb = (char*)d_ws;
    size_t o = 0;
    auto take = [&](size_t bytes) -> char* {
        char* p = wsb + o;
        o += (bytes + 255) & ~(size_t)255;
        return p;
    };
    int*      bkt_cnt    = (int*)take(NBMAX * 4);             // zeroed each call
    int*      bkt_base   = (int*)take((NBMAX + 1) * 4);
    int*      hist_g     = (int*)take((size_t)gB * NBMAX * 4);
    int*      rp         = (int*)take((size_t)(N + 1) * 4);
    float*    dis        = (float*)take((size_t)N * 4);
    uint2*    stage      = (uint2*)take((size_t)E * 8);       // dead after bsort; xw aliases it
    uint_t*   edges      = (uint_t*)take((size_t)E * 4);      // compact 4B records
    ushort_t* h          = (ushort_t*)take((size_t)N * 96 * 2);
    ushort_t* Wt1        = (ushort_t*)take(96 * 128 * 2);
    ushort_t* Wt2        = (ushort_t*)take(96 * 96 * 2);
    ushort_t* Wt3        = (ushort_t*)take(32 * 96 * 2);
    ushort_t* xw         = (ushort_t*)stage;                  // alias (E*8 >= 8*N*12*2)

    const int gM = (N + 63) / 64;

    hipMemsetAsync(bkt_cnt, 0, NBMAX * 4, stream);

    // CSR build: hist (+rows) -> scan -> rebase -> deterministic scatter -> sort
    gcn_bhist<<<gB, 1024, 0, stream>>>(ei, bkt_cnt, hist_g, E, NB);
    gcn_wt<<<48, 256, 0, stream>>>(W1, W2, W3, Wt1, Wt2, Wt3);
    gcn_bscan<<<1, 256, 0, stream>>>(bkt_cnt, bkt_base, rp, NB, N, E);
    gcn_brebase<<<(NB + 255) / 256, 256, 0, stream>>>(hist_g, bkt_base, NB, gB);
    gcn_bscatter<<<gB, 1024, 0, stream>>>(ei, ew, hist_g, stage, E, NB);
    gcn_bsort<<<NB, 256, 0, stream>>>(stage, edges, bkt_base, rp, dis, N);

    // agg grids: 8 (resp. 4) feature slices, slice = blockIdx % 8 (XCD-pinned)
    const int gA96 = ((N + 63) / 64) * 8;      // 1563 node-groups x 8 slices
    const int gA32 = ((N + 255) / 256) * 4;    // 391 node-groups x 4 slices

    // layer 1: x[.,128](fp32) -> xws slice-major [8][N][12](bf16, dis-scaled)
    gcn_gemm_mfma<128, 96, 96, 12, true><<<gM, 256, 0, stream>>>(x, Wt1, dis, xw, N);
    gcn_agg96<<<gA96, 192, 0, stream>>>(xw, rp, edges, dis, b1, h, N);

    // layer 2
    gcn_gemm_mfma<96, 96, 96, 12, false><<<gM, 256, 0, stream>>>(h, Wt2, dis, xw, N);
    gcn_agg96<<<gA96, 192, 0, stream>>>(xw, rp, edges, dis, b2, h, N);

    // layer 3 (FOUT=30 padded to 32; xws slice-major [4][N][8])
    gcn_gemm_mfma<96, 30, 32, 8, false><<<gM, 256, 0, stream>>>(h, Wt3, dis, xw, N);
    gcn_agg32<<<gA32, 256, 0, stream>>>(xw, rp, edges, dis, b3, h, N);

    // mean pool + classifier + softmax
    gcn_pool<<<256, 256, 0, stream>>>(h, bat, Wf, bf_, out, N);
}

// Round 3
// 596.358 us; speedup vs baseline: 1.6697x; 1.6697x over previous
//
#include <hip/hip_runtime.h>
#include <hip/hip_bf16.h>

typedef unsigned short ushort_t;
typedef unsigned int uint_t;
typedef unsigned long long u64_t;

typedef __attribute__((ext_vector_type(8))) short bf16x8;   // 8 bf16 (4 VGPRs)
typedef __attribute__((ext_vector_type(4))) float floatx4;  // MFMA C/D

#define DI __device__ __forceinline__

// NOTE: record packing uses 17 bits for src -> requires N < 131072. (N=100000)
// Final edge record (4B): bits 0..16 = src, bits 17..31 = bf16(|w|) sans sign
// (w >= 0 so bf16 sign bit is always 0; decode = (rec>>1) & 0xFFFF0000).
#define NPB 128          // nodes per bucket
#define NBMAX 1024       // max buckets (N <= 131072)
#define CH 8             // src chunks (kept in sort key; harmless ordering)

// bf16 bits -> f32
DI float b2f(uint_t lo16) {
    union { uint_t u; float f; } v; v.u = lo16 << 16; return v.f;
}
// f32 -> bf16 bits, round-to-nearest-even
DI ushort_t f2b(float f) {
    union { float f; uint_t u; } v; v.f = f;
    uint_t u = v.u;
    uint_t r = (u + 0x7fffu + ((u >> 16) & 1u)) >> 16;
    return (ushort_t)r;
}
// decode 15-bit packed |w| from a 4B edge record
DI float wdec(uint_t rec) {
    union { uint_t u; float f; } v;
    v.u = (rec >> 1) & 0xFFFF0000u;
    return v.f;
}

// fma 8 bf16 feats (packed in uint4) into acc[8]
DI void fma8(float* a, uint4 v, float nm) {
    a[0] += nm * b2f(v.x & 0xffffu); a[1] += nm * b2f(v.x >> 16);
    a[2] += nm * b2f(v.y & 0xffffu); a[3] += nm * b2f(v.y >> 16);
    a[4] += nm * b2f(v.z & 0xffffu); a[5] += nm * b2f(v.z >> 16);
    a[6] += nm * b2f(v.w & 0xffffu); a[7] += nm * b2f(v.w >> 16);
}

// ---------------- P1: bucket histogram (LDS-binned) --------------------------
// Persists this block's per-bucket counts row to hist_g for deterministic scatter.
__global__ __launch_bounds__(1024) void gcn_bhist(
    const int* __restrict__ ei, int* __restrict__ bkt_cnt,
    int* __restrict__ hist_g, int E, int NB)
{
    __shared__ int hist[NBMAX];
    int t = threadIdx.x;
    for (int b = t; b < NB; b += 1024) hist[b] = 0;
    __syncthreads();
    int base = blockIdx.x * 32768;
    int lim = min(32768, E - base);
    for (int i = t; i < lim; i += 1024) {
        int d = ei[(size_t)E + base + i];
        atomicAdd(&hist[d >> 7], 1);
    }
    __syncthreads();
    int* row = hist_g + (size_t)blockIdx.x * NBMAX;
    for (int b = t; b < NB; b += 1024) {
        int c = hist[b];
        row[b] = c;
        if (c) atomicAdd(&bkt_cnt[b], c);
    }
}

// ---------------- P2: scan bucket counts -> bases ----------------------------
__global__ __launch_bounds__(256) void gcn_bscan(
    const int* __restrict__ bkt_cnt, int* __restrict__ bkt_base,
    int* __restrict__ rp, int NB, int N, int E)
{
    __shared__ int lds[256];
    int t = threadIdx.x;
    int v[4]; int s = 0;
    #pragma unroll
    for (int j = 0; j < 4; j++) {
        int b = t * 4 + j;
        v[j] = (b < NB) ? bkt_cnt[b] : 0;
        s += v[j];
    }
    lds[t] = s;
    __syncthreads();
    #pragma unroll
    for (int off = 1; off < 256; off <<= 1) {
        int y = (t >= off) ? lds[t - off] : 0;
        __syncthreads();
        lds[t] += y;
        __syncthreads();
    }
    int run = lds[t] - s;
    #pragma unroll
    for (int j = 0; j < 4; j++) {
        int b = t * 4 + j;
        if (b < NB) bkt_base[b] = run;
        run += v[j];
    }
    if (t == 255) { bkt_base[NB] = E; rp[N] = E; }
}

// ---------------- P2b: rebase per-block rows -> deterministic write bases ----
__global__ __launch_bounds__(256) void gcn_brebase(
    int* __restrict__ hist_g, const int* __restrict__ bkt_base, int NB, int nrows)
{
    int k = blockIdx.x * 256 + threadIdx.x;
    if (k >= NB) return;
    int run = bkt_base[k];
    for (int r = 0; r < nrows; r++) {
        int* p = hist_g + (size_t)r * NBMAX + k;
        int v = *p;
        *p = run;
        run += v;
    }
}

// ---------------- P3: scatter records into bucket regions (no global atomics) -
// record: x = src | (dst&127)<<17 ; y = |w| (f32 bits). Per-edge atomics are LDS.
__global__ __launch_bounds__(1024) void gcn_bscatter(
    const int* __restrict__ ei, const float* __restrict__ ew,
    const int* __restrict__ hist_g, uint2* __restrict__ stage, int E, int NB)
{
    __shared__ int cur[NBMAX];
    int t = threadIdx.x;
    const int* row = hist_g + (size_t)blockIdx.x * NBMAX;
    for (int b = t; b < NB; b += 1024) cur[b] = row[b];
    __syncthreads();
    int base = blockIdx.x * 32768;
    int lim = min(32768, E - base);
    for (int i = t; i < lim; i += 1024) {
        int e = base + i;
        int s = ei[e];
        int d = ei[(size_t)E + e];
        float w = fabsf(ew[e]);
        int pos = atomicAdd(&cur[d >> 7], 1);
        uint2 rec;
        rec.x = (uint_t)s | ((uint_t)(d & 127) << 17);
        rec.y = __float_as_uint(w);
        stage[pos] = rec;
    }
}

// ---------------- P4: per-bucket counting sort by (node, src-chunk) ----------
// Emits rp[n] (node boundaries; global-contiguous across buckets), dis, and the
// compact 4B edge records (src | bf16(|w|)<<17). f32 w still feeds deg/dis.
__global__ __launch_bounds__(256) void gcn_bsort(
    const uint2* __restrict__ stage, uint_t* __restrict__ edges,
    const int* __restrict__ bkt_base, int* __restrict__ rp,
    float* __restrict__ dis, int N)
{
    int b = blockIdx.x;
    int base = bkt_base[b], end = bkt_base[b + 1];
    int cnte = end - base;
    int n0 = b << 7;
    __shared__ int cnt[NPB * CH];     // 1024 bins
    __shared__ float wsum[NPB];
    __shared__ int scn[256];
    __shared__ int cur[NPB * CH];
    int t = threadIdx.x;
    for (int i = t; i < NPB * CH; i += 256) cnt[i] = 0;
    if (t < NPB) wsum[t] = 0.0f;
    __syncthreads();
    for (int i = t; i < cnte; i += 256) {
        uint2 r = stage[base + i];
        int dl = (r.x >> 17) & 127;
        int ch = (r.x & 0x1FFFF) >> 14;
        atomicAdd(&cnt[dl * CH + ch], 1);
        atomicAdd(&wsum[dl], __uint_as_float(r.y));
    }
    __syncthreads();
    int v0 = cnt[t * 4], v1 = cnt[t * 4 + 1], v2 = cnt[t * 4 + 2], v3 = cnt[t * 4 + 3];
    int s = v0 + v1 + v2 + v3;
    scn[t] = s;
    __syncthreads();
    #pragma unroll
    for (int off = 1; off < 256; off <<= 1) {
        int y = (t >= off) ? scn[t - off] : 0;
        __syncthreads();
        scn[t] += y;
        __syncthreads();
    }
    int e0 = scn[t] - s;
    int e1 = e0 + v0, e2 = e1 + v1, e3 = e2 + v2;
    cur[t * 4]     = base + e0;
    cur[t * 4 + 1] = base + e1;
    cur[t * 4 + 2] = base + e2;
    cur[t * 4 + 3] = base + e3;
    // node dl's start = prefix of bin dl*CH (CH=8 -> bin 8dl, thread 2dl, j=0)
    if ((t & 1) == 0) {
        int dl = t >> 1;
        int n = n0 + dl;
        if (n < N) {
            rp[n] = base + e0;
            dis[n] = rsqrtf(wsum[dl] + 1.0f);
        }
    }
    __syncthreads();
    for (int i = t; i < cnte; i += 256) {
        uint2 r = stage[base + i];
        int dl = (r.x >> 17) & 127;
        int ch = (r.x & 0x1FFFF) >> 14;
        int pos = atomicAdd(&cur[dl * CH + ch], 1);
        // compact 4B record: src (17b) | sign-stripped bf16(|w|) (15b)
        edges[pos] = (r.x & 0x1FFFFu) | ((uint_t)f2b(__uint_as_float(r.y)) << 17);
    }
}

// ---------------- weight transpose + bf16 convert (once per call, tiny) -------
__global__ __launch_bounds__(256) void gcn_wt(
    const float* __restrict__ W1, const float* __restrict__ W2,
    const float* __restrict__ W3,
    ushort_t* __restrict__ Wt1, ushort_t* __restrict__ Wt2,
    ushort_t* __restrict__ Wt3)
{
    int i = blockIdx.x * 256 + threadIdx.x;
    if (i < 96 * 128) {                       // layer 1: Wt1[96][128]
        int n = i / 128, k = i % 128;
        Wt1[i] = f2b(W1[k * 96 + n]);
    }
    if (i < 96 * 96) {                        // layer 2: Wt2[96][96]
        int n = i / 96, k = i % 96;
        Wt2[i] = f2b(W2[k * 96 + n]);
    }
    if (i < 32 * 96) {                        // layer 3: Wt3[32][96], pad rows 30,31
        int n = i / 96, k = i % 96;
        Wt3[i] = f2b((n < 30) ? W3[k * 30 + n] : 0.0f);
    }
}

// ---------------- MFMA GEMM: Y[row,:] = dis[row] * (X[row,:] @ W) ------------
template<int K, int FOUT, int NTR, int FOUTP, bool XF32>
__global__ __launch_bounds__(256) void gcn_gemm_mfma(
    const void* __restrict__ Xv, const ushort_t* __restrict__ Wt,
    const float* __restrict__ dis, ushort_t* __restrict__ Y, int N)
{
    constexpr int KS = K + 8;
    constexpr int KT = K / 32;
    constexpr int NT = NTR / 16;
    __shared__ ushort_t xs[64 * KS];
    __shared__ ushort_t ws[NTR * KS];

    int t = threadIdx.x;
    int mbase = blockIdx.x * 64;

    {
        constexpr int TOT = NTR * (K / 8);
        const uint4* wg = (const uint4*)Wt;
        for (int i = t; i < TOT; i += 256) {
            int r = i / (K / 8), c8 = i % (K / 8);
            *(uint4*)(ws + r * KS + c8 * 8) = wg[i];
        }
    }
    if (XF32) {
        const float* X = (const float*)Xv;
        constexpr int TOT = 64 * (K / 4);
        for (int i = t; i < TOT; i += 256) {
            int row = i / (K / 4), c4 = i % (K / 4);
            int rg = mbase + row; if (rg >= N) rg = N - 1;
            float4 v = *(const float4*)(X + (size_t)rg * K + c4 * 4);
            uint2 pv;
            pv.x = (uint_t)f2b(v.x) | ((uint_t)f2b(v.y) << 16);
            pv.y = (uint_t)f2b(v.z) | ((uint_t)f2b(v.w) << 16);
            *(uint2*)(xs + row * KS + c4 * 4) = pv;
        }
    } else {
        const ushort_t* X = (const ushort_t*)Xv;
        constexpr int TOT = 64 * (K / 8);
        for (int i = t; i < TOT; i += 256) {
            int row = i / (K / 8), c8 = i % (K / 8);
            int rg = mbase + row; if (rg >= N) rg = N - 1;
            *(uint4*)(xs + row * KS + c8 * 8) = *(const uint4*)(X + (size_t)rg * K + c8 * 8);
        }
    }
    __syncthreads();

    int wave = t >> 6;
    int lane = t & 63;
    int l15 = lane & 15, quad = lane >> 4;

    bf16x8 af[KT];
    #pragma unroll
    for (int kt = 0; kt < KT; kt++)
        af[kt] = *(const bf16x8*)(xs + (wave * 16 + l15) * KS + kt * 32 + quad * 8);

    floatx4 acc[NT];
    #pragma unroll
    for (int nt = 0; nt < NT; nt++) acc[nt] = (floatx4){0.f, 0.f, 0.f, 0.f};

    #pragma unroll
    for (int nt = 0; nt < NT; nt++) {
        #pragma unroll
        for (int kt = 0; kt < KT; kt++) {
            bf16x8 bfr = *(const bf16x8*)(ws + (nt * 16 + l15) * KS + kt * 32 + quad * 8);
            acc[nt] = __builtin_amdgcn_mfma_f32_16x16x32_bf16(af[kt], bfr, acc[nt], 0, 0, 0);
        }
    }

    float dsc[4];
    #pragma unroll
    for (int r = 0; r < 4; r++) {
        int row = mbase + wave * 16 + quad * 4 + r;
        dsc[r] = (row < N) ? dis[row] : 0.0f;
    }
    #pragma unroll
    for (int nt = 0; nt < NT; nt++) {
        int col = nt * 16 + l15;
        #pragma unroll
        for (int r = 0; r < 4; r++) {
            int row = mbase + wave * 16 + quad * 4 + r;
            if (row < N) {
                float v = (col < FOUT) ? acc[nt][r] * dsc[r] : 0.0f;
                Y[(size_t)row * FOUTP + col] = f2b(v);
            }
        }
    }
}

// ---------------- aggregation: node-parallel, forced 8-deep gather MLP --------
// R6 structure (max wave parallelism). R2 lesson: feature-slice/XCD partition
// regressed 2.5x (narrow 8B gathers, doubled lane-ops, cross-XCD partial-line
// writes). R0's VGPR_Count=36 proved the compiler SERIALIZED the 8 gather
// chains (8 live uint4 alone = 32 VGPR); sched_barrier(0) after the load
// cluster forces all 8 gathers in flight (VGPR ~60, still full-occupancy band).
// 4B edge records halve the record stream vs R0's u64.
// XWS = dis-scaled xw. H[n] = relu(b + dis[n]*(sum_e w*XWS[src] + XWS[n])).
template<int FOUT, int FOUTP, int LPN, int BLK>
__global__ __launch_bounds__(BLK) void gcn_agg(
    const ushort_t* __restrict__ XWS, const int* __restrict__ rp,
    const uint_t* __restrict__ edges,
    const float* __restrict__ dis, const float* __restrict__ bias,
    ushort_t* __restrict__ H, int N)
{
    constexpr int NC = FOUTP / 8;           // uint4 per row (== LPN)
    int n = blockIdx.x * (BLK / LPN) + threadIdx.x / LPN;
    int c = threadIdx.x % LPN;
    if (n >= N) return;
    const uint4* xwc = (const uint4*)XWS;

    int beg = rp[n], end = rp[n + 1];
    float a[8];
    #pragma unroll
    for (int j = 0; j < 8; j++) a[j] = 0.0f;

    int e = beg;
    for (; e + 8 <= end; e += 8) {
        uint_t r0 = __builtin_nontemporal_load(edges + e);
        uint_t r1 = __builtin_nontemporal_load(edges + e + 1);
        uint_t r2 = __builtin_nontemporal_load(edges + e + 2);
        uint_t r3 = __builtin_nontemporal_load(edges + e + 3);
        uint_t r4 = __builtin_nontemporal_load(edges + e + 4);
        uint_t r5 = __builtin_nontemporal_load(edges + e + 5);
        uint_t r6 = __builtin_nontemporal_load(edges + e + 6);
        uint_t r7 = __builtin_nontemporal_load(edges + e + 7);
        uint4 v0 = xwc[(size_t)(r0 & 0x1FFFFu) * NC + c];
        uint4 v1 = xwc[(size_t)(r1 & 0x1FFFFu) * NC + c];
        uint4 v2 = xwc[(size_t)(r2 & 0x1FFFFu) * NC + c];
        uint4 v3 = xwc[(size_t)(r3 & 0x1FFFFu) * NC + c];
        uint4 v4 = xwc[(size_t)(r4 & 0x1FFFFu) * NC + c];
        uint4 v5 = xwc[(size_t)(r5 & 0x1FFFFu) * NC + c];
        uint4 v6 = xwc[(size_t)(r6 & 0x1FFFFu) * NC + c];
        uint4 v7 = xwc[(size_t)(r7 & 0x1FFFFu) * NC + c];
        __builtin_amdgcn_sched_barrier(0);   // keep all 8 gathers in flight
        fma8(a, v0, wdec(r0));
        fma8(a, v1, wdec(r1));
        fma8(a, v2, wdec(r2));
        fma8(a, v3, wdec(r3));
        fma8(a, v4, wdec(r4));
        fma8(a, v5, wdec(r5));
        fma8(a, v6, wdec(r6));
        fma8(a, v7, wdec(r7));
    }
    for (; e + 4 <= end; e += 4) {
        uint_t r0 = __builtin_nontemporal_load(edges + e);
        uint_t r1 = __builtin_nontemporal_load(edges + e + 1);
        uint_t r2 = __builtin_nontemporal_load(edges + e + 2);
        uint_t r3 = __builtin_nontemporal_load(edges + e + 3);
        uint4 v0 = xwc[(size_t)(r0 & 0x1FFFFu) * NC + c];
        uint4 v1 = xwc[(size_t)(r1 & 0x1FFFFu) * NC + c];
        uint4 v2 = xwc[(size_t)(r2 & 0x1FFFFu) * NC + c];
        uint4 v3 = xwc[(size_t)(r3 & 0x1FFFFu) * NC + c];
        __builtin_amdgcn_sched_barrier(0);
        fma8(a, v0, wdec(r0));
        fma8(a, v1, wdec(r1));
        fma8(a, v2, wdec(r2));
        fma8(a, v3, wdec(r3));
    }
    for (; e < end; e++) {
        uint_t r0 = __builtin_nontemporal_load(edges + e);
        uint4 v0 = xwc[(size_t)(r0 & 0x1FFFFu) * NC + c];
        fma8(a, v0, wdec(r0));
    }

    uint4 sv = xwc[(size_t)n * NC + c];
    fma8(a, sv, 1.0f);                 // + XWS[n]
    float d = dis[n];
    int f0 = c * 8;
    uint_t o[4];
    #pragma unroll
    for (int p = 0; p < 4; p++) {
        float rA = (f0 + 2 * p     < FOUT) ? fmaxf(a[2 * p]     * d + bias[f0 + 2 * p],     0.f) : 0.f;
        float rB = (f0 + 2 * p + 1 < FOUT) ? fmaxf(a[2 * p + 1] * d + bias[f0 + 2 * p + 1], 0.f) : 0.f;
        o[p] = (uint_t)f2b(rA) | ((uint_t)f2b(rB) << 16);
    }
    uint4 ov = {o[0], o[1], o[2], o[3]};
    *((uint4*)H + (size_t)n * NC + c) = ov;
}

// ---------------- mean-pool per graph + final linear + softmax ----------------
__global__ __launch_bounds__(256) void gcn_pool(
    const ushort_t* __restrict__ H, const int* __restrict__ batch,
    const float* __restrict__ Wf, const float* __restrict__ bf_,
    float* __restrict__ out, int N)
{
    __shared__ float pool[32];
    int g = blockIdx.x;
    int t = threadIdx.x;

    int lo = 0, hi = N;
    while (lo < hi) { int mid = (lo + hi) >> 1; if (batch[mid] < g) lo = mid + 1; else hi = mid; }
    int start = lo;
    lo = 0; hi = N;
    while (lo < hi) { int mid = (lo + hi) >> 1; if (batch[mid] < g + 1) lo = mid + 1; else hi = mid; }
    int end = lo;

    float acc[32];
    #pragma unroll
    for (int f = 0; f < 32; f++) acc[f] = 0.0f;
    for (int i = start + t; i < end; i += 256) {
        const uint2* hr = (const uint2*)H + (size_t)i * 8;
        #pragma unroll
        for (int q = 0; q < 8; q++) {
            uint2 v = hr[q];
            acc[4 * q + 0] += b2f(v.x & 0xffffu);
            acc[4 * q + 1] += b2f(v.x >> 16);
            acc[4 * q + 2] += b2f(v.y & 0xffffu);
            acc[4 * q + 3] += b2f(v.y >> 16);
        }
    }
    #pragma unroll
    for (int f = 0; f < 32; f++) {
        float v = acc[f];
        v += __shfl_down(v, 32, 64);
        v += __shfl_down(v, 16, 64);
        v += __shfl_down(v, 8, 64);
        v += __shfl_down(v, 4, 64);
        v += __shfl_down(v, 2, 64);
        v += __shfl_down(v, 1, 64);
        acc[f] = v;
    }
    if (t < 32) pool[t] = 0.0f;
    __syncthreads();
    if ((t & 63) == 0) {
        #pragma unroll
        for (int f = 0; f < 30; f++) atomicAdd(&pool[f], acc[f]);
    }
    __syncthreads();
    if (t == 0) {
        float inv = 1.0f / fmaxf((float)(end - start), 1.0f);
        float lg[10];
        #pragma unroll
        for (int j = 0; j < 10; j++) lg[j] = bf_[j];
        for (int f = 0; f < 30; f++) {
            float p = pool[f] * inv;
            #pragma unroll
            for (int j = 0; j < 10; j++) lg[j] += p * Wf[f * 10 + j];
        }
        float m = lg[0];
        #pragma unroll
        for (int j = 1; j < 10; j++) m = fmaxf(m, lg[j]);
        float s = 0.f;
        #pragma unroll
        for (int j = 0; j < 10; j++) { lg[j] = __expf(lg[j] - m); s += lg[j]; }
        float is = 1.0f / s;
        #pragma unroll
        for (int j = 0; j < 10; j++) out[g * 10 + j] = lg[j] * is;
    }
}

extern "C" void kernel_launch(void* const* d_in, const int* in_sizes, int n_in,
                              void* d_out, int out_size, void* d_ws, size_t ws_size,
                              hipStream_t stream) {
    (void)n_in; (void)out_size; (void)ws_size;
    const float* x   = (const float*)d_in[0];
    const int*   ei  = (const int*)d_in[1];
    const float* ew  = (const float*)d_in[2];
    const int*   bat = (const int*)d_in[3];
    const float* W1  = (const float*)d_in[4];
    const float* b1  = (const float*)d_in[5];
    const float* W2  = (const float*)d_in[6];
    const float* b2  = (const float*)d_in[7];
    const float* W3  = (const float*)d_in[8];
    const float* b3  = (const float*)d_in[9];
    const float* Wf  = (const float*)d_in[10];
    const float* bf_ = (const float*)d_in[11];
    float* out = (float*)d_out;

    const int N = in_sizes[3];       // 100000
    const int E = in_sizes[2];       // 3200000
    const int NB = (N + NPB - 1) / NPB;   // 782
    const int gB = (E + 32767) / 32768;   // 98

    char* wsb = (char*)d_ws;
    size_t o = 0;
    auto take = [&](size_t bytes) -> char* {
        char* p = wsb + o;
        o += (bytes + 255) & ~(size_t)255;
        return p;
    };
    int*      bkt_cnt    = (int*)take(NBMAX * 4);             // zeroed each call
    int*      bkt_base   = (int*)take((NBMAX + 1) * 4);
    int*      hist_g     = (int*)take((size_t)gB * NBMAX * 4);
    int*      rp         = (int*)take((size_t)(N + 1) * 4);
    float*    dis        = (float*)take((size_t)N * 4);
    uint2*    stage      = (uint2*)take((size_t)E * 8);       // dead after bsort; xw aliases it
    uint_t*   edges      = (uint_t*)take((size_t)E * 4);      // compact 4B records
    ushort_t* h          = (ushort_t*)take((size_t)N * 96 * 2);
    ushort_t* Wt1        = (ushort_t*)take(96 * 128 * 2);
    ushort_t* Wt2        = (ushort_t*)take(96 * 96 * 2);
    ushort_t* Wt3        = (ushort_t*)take(32 * 96 * 2);
    ushort_t* xw         = (ushort_t*)stage;                  // alias (E*8 >= N*96*2)

    const int gM = (N + 63) / 64;

    hipMemsetAsync(bkt_cnt, 0, NBMAX * 4, stream);

    // CSR build: hist (+rows) -> scan -> rebase -> deterministic scatter -> sort
    gcn_bhist<<<gB, 1024, 0, stream>>>(ei, bkt_cnt, hist_g, E, NB);
    gcn_wt<<<48, 256, 0, stream>>>(W1, W2, W3, Wt1, Wt2, Wt3);
    gcn_bscan<<<1, 256, 0, stream>>>(bkt_cnt, bkt_base, rp, NB, N, E);
    gcn_brebase<<<(NB + 255) / 256, 256, 0, stream>>>(hist_g, bkt_base, NB, gB);
    gcn_bscatter<<<gB, 1024, 0, stream>>>(ei, ew, hist_g, stage, E, NB);
    gcn_bsort<<<NB, 256, 0, stream>>>(stage, edges, bkt_base, rp, dis, N);

    // agg grids: oversubscribed (max wave parallelism)
    const int gA96 = (N + 15) / 16;    // 6250 blocks x 3 waves
    const int gA32 = (N + 63) / 64;    // 1563 blocks x 4 waves

    // layer 1: x[.,128](fp32) -> xws[.,96](bf16, dis-scaled) -> h[.,96](bf16)
    gcn_gemm_mfma<128, 96, 96, 96, true><<<gM, 256, 0, stream>>>(x, Wt1, dis, xw, N);
    gcn_agg<96, 96, 12, 192><<<gA96, 192, 0, stream>>>(xw, rp, edges, dis, b1, h, N);

    // layer 2
    gcn_gemm_mfma<96, 96, 96, 96, false><<<gM, 256, 0, stream>>>(h, Wt2, dis, xw, N);
    gcn_agg<96, 96, 12, 192><<<gA96, 192, 0, stream>>>(xw, rp, edges, dis, b2, h, N);

    // layer 3 (FOUT=30 padded to 32)
    gcn_gemm_mfma<96, 30, 32, 32, false><<<gM, 256, 0, stream>>>(h, Wt3, dis, xw, N);
    gcn_agg<30, 32, 4, 256><<<gA32, 256, 0, stream>>>(xw, rp, edges, dis, b3, h, N);

    // mean pool + classifier + softmax
    gcn_pool<<<256, 256, 0, stream>>>(h, bat, Wf, bf_, out, N);
}

// Round 4
// 580.331 us; speedup vs baseline: 1.7158x; 1.0276x over previous
//
#include <hip/hip_runtime.h>
#include <hip/hip_bf16.h>

typedef unsigned short ushort_t;
typedef unsigned int uint_t;
typedef unsigned long long u64_t;

typedef __attribute__((ext_vector_type(8))) short bf16x8;   // 8 bf16 (4 VGPRs)
typedef __attribute__((ext_vector_type(4))) float floatx4;  // MFMA C/D

#define DI __device__ __forceinline__

// NOTE: record packing uses 17 bits for src -> requires N < 131072. (N=100000)
// Final edge record (4B): bits 0..16 = src, bits 17..31 = bf16(|w|) sans sign
// (w >= 0 so bf16 sign bit is always 0; decode = (rec>>1) & 0xFFFF0000).
#define NPB 128          // nodes per bucket
#define NBMAX 1024       // max buckets (N <= 131072)
#define CH 16            // src chunks: 1.2MB sync window (< 4MB L2) for agg L2 hits
#define EPB 16384        // edges per hist/scatter block (196 blocks -> CU coverage)

// bf16 bits -> f32
DI float b2f(uint_t lo16) {
    union { uint_t u; float f; } v; v.u = lo16 << 16; return v.f;
}
// f32 -> bf16 bits, round-to-nearest-even
DI ushort_t f2b(float f) {
    union { float f; uint_t u; } v; v.f = f;
    uint_t u = v.u;
    uint_t r = (u + 0x7fffu + ((u >> 16) & 1u)) >> 16;
    return (ushort_t)r;
}
// decode 15-bit packed |w| from a 4B edge record
DI float wdec(uint_t rec) {
    union { uint_t u; float f; } v;
    v.u = (rec >> 1) & 0xFFFF0000u;
    return v.f;
}

// fma 8 bf16 feats (packed in uint4) into acc[8]
DI void fma8(float* a, uint4 v, float nm) {
    a[0] += nm * b2f(v.x & 0xffffu); a[1] += nm * b2f(v.x >> 16);
    a[2] += nm * b2f(v.y & 0xffffu); a[3] += nm * b2f(v.y >> 16);
    a[4] += nm * b2f(v.z & 0xffffu); a[5] += nm * b2f(v.z >> 16);
    a[6] += nm * b2f(v.w & 0xffffu); a[7] += nm * b2f(v.w >> 16);
}

// ---------------- P1: bucket histogram (LDS-binned) --------------------------
// Persists this block's per-bucket counts COLUMN to hist_t (transposed:
// hist_t[bucket][block]) so brebase scans contiguous rows.
__global__ __launch_bounds__(1024) void gcn_bhist(
    const int* __restrict__ ei, int* __restrict__ bkt_cnt,
    int* __restrict__ hist_t, int E, int NB, int nrows)
{
    __shared__ int hist[NBMAX];
    int t = threadIdx.x;
    for (int b = t; b < NB; b += 1024) hist[b] = 0;
    __syncthreads();
    int base = blockIdx.x * EPB;
    int lim = min(EPB, E - base);
    for (int i = t; i < lim; i += 1024) {
        int d = ei[(size_t)E + base + i];
        atomicAdd(&hist[d >> 7], 1);
    }
    __syncthreads();
    for (int b = t; b < NB; b += 1024) {
        int c = hist[b];
        hist_t[(size_t)b * nrows + blockIdx.x] = c;
        if (c) atomicAdd(&bkt_cnt[b], c);
    }
}

// ---------------- P2: scan bucket counts -> bases ----------------------------
__global__ __launch_bounds__(256) void gcn_bscan(
    const int* __restrict__ bkt_cnt, int* __restrict__ bkt_base,
    int* __restrict__ rp, int NB, int N, int E)
{
    __shared__ int lds[256];
    int t = threadIdx.x;
    int v[4]; int s = 0;
    #pragma unroll
    for (int j = 0; j < 4; j++) {
        int b = t * 4 + j;
        v[j] = (b < NB) ? bkt_cnt[b] : 0;
        s += v[j];
    }
    lds[t] = s;
    __syncthreads();
    #pragma unroll
    for (int off = 1; off < 256; off <<= 1) {
        int y = (t >= off) ? lds[t - off] : 0;
        __syncthreads();
        lds[t] += y;
        __syncthreads();
    }
    int run = lds[t] - s;
    #pragma unroll
    for (int j = 0; j < 4; j++) {
        int b = t * 4 + j;
        if (b < NB) bkt_base[b] = run;
        run += v[j];
    }
    if (t == 255) { bkt_base[NB] = E; rp[N] = E; }
}

// ---------------- P2b: rebase per-block rows -> deterministic write bases ----
// Transposed layout: each bucket's per-block counts are a contiguous row of
// nrows ints -> vectorized uint4 loads + register scan (was a ~30us dependent
// global RMW chain per thread in the [row][bucket] layout).
__global__ __launch_bounds__(256) void gcn_brebase(
    int* __restrict__ hist_t, const int* __restrict__ bkt_base, int NB, int nrows)
{
    int k = blockIdx.x * 256 + threadIdx.x;
    if (k >= NB) return;
    uint4* p = (uint4*)(hist_t + (size_t)k * nrows);
    int run = bkt_base[k];
    int n4 = nrows >> 2;           // nrows % 4 == 0 (EPB chosen so)
    for (int r4 = 0; r4 < n4; r4++) {
        uint4 v = p[r4];
        uint4 w;
        w.x = run; run += v.x;
        w.y = run; run += v.y;
        w.z = run; run += v.z;
        w.w = run; run += v.w;
        p[r4] = w;
    }
}

// ---------------- P3: scatter records into bucket regions (no global atomics) -
// record: x = src | (dst&127)<<17 ; y = |w| (f32 bits). Per-edge atomics are LDS.
__global__ __launch_bounds__(1024) void gcn_bscatter(
    const int* __restrict__ ei, const float* __restrict__ ew,
    const int* __restrict__ hist_t, uint2* __restrict__ stage, int E, int NB, int nrows)
{
    __shared__ int cur[NBMAX];
    int t = threadIdx.x;
    for (int b = t; b < NB; b += 1024)
        cur[b] = hist_t[(size_t)b * nrows + blockIdx.x];
    __syncthreads();
    int base = blockIdx.x * EPB;
    int lim = min(EPB, E - base);
    for (int i = t; i < lim; i += 1024) {
        int e = base + i;
        int s = ei[e];
        int d = ei[(size_t)E + e];
        float w = fabsf(ew[e]);
        int pos = atomicAdd(&cur[d >> 7], 1);
        uint2 rec;
        rec.x = (uint_t)s | ((uint_t)(d & 127) << 17);
        rec.y = __float_as_uint(w);
        stage[pos] = rec;
    }
}

// ---------------- P4: per-bucket counting sort by (node, src-chunk) ----------
// Emits rp[n] (node boundaries; global-contiguous across buckets), dis, and the
// compact 4B edge records (src | bf16(|w|)<<17). f32 w still feeds deg/dis.
// CH=16 chunks: agg's concurrent blocks walk chunk phases roughly in sync, so
// the live src window is ~1.2MB per XCD L2.
__global__ __launch_bounds__(256) void gcn_bsort(
    const uint2* __restrict__ stage, uint_t* __restrict__ edges,
    const int* __restrict__ bkt_base, int* __restrict__ rp,
    float* __restrict__ dis, int N)
{
    int b = blockIdx.x;
    int base = bkt_base[b], end = bkt_base[b + 1];
    int cnte = end - base;
    int n0 = b << 7;
    __shared__ int cnt[NPB * CH];     // 2048 bins
    __shared__ float wsum[NPB];
    __shared__ int scn[256];
    __shared__ int cur[NPB * CH];
    int t = threadIdx.x;
    for (int i = t; i < NPB * CH; i += 256) cnt[i] = 0;
    if (t < NPB) wsum[t] = 0.0f;
    __syncthreads();
    for (int i = t; i < cnte; i += 256) {
        uint2 r = stage[base + i];
        int dl = (r.x >> 17) & 127;
        int ch = (r.x & 0x1FFFF) >> 13;          // 16 chunks of src range
        atomicAdd(&cnt[dl * CH + ch], 1);
        atomicAdd(&wsum[dl], __uint_as_float(r.y));
    }
    __syncthreads();
    int v[8]; int s = 0;
    #pragma unroll
    for (int j = 0; j < 8; j++) { v[j] = cnt[t * 8 + j]; s += v[j]; }
    scn[t] = s;
    __syncthreads();
    #pragma unroll
    for (int off = 1; off < 256; off <<= 1) {
        int y = (t >= off) ? scn[t - off] : 0;
        __syncthreads();
        scn[t] += y;
        __syncthreads();
    }
    int e0 = scn[t] - s;
    int run = e0;
    #pragma unroll
    for (int j = 0; j < 8; j++) { cur[t * 8 + j] = base + run; run += v[j]; }
    // node dl's start = prefix of bin dl*CH (CH=16 -> bin 16dl = thread 2dl, j=0)
    if ((t & 1) == 0) {
        int dl = t >> 1;
        int n = n0 + dl;
        if (n < N) {
            rp[n] = base + e0;
            dis[n] = rsqrtf(wsum[dl] + 1.0f);
        }
    }
    __syncthreads();
    for (int i = t; i < cnte; i += 256) {
        uint2 r = stage[base + i];
        int dl = (r.x >> 17) & 127;
        int ch = (r.x & 0x1FFFF) >> 13;
        int pos = atomicAdd(&cur[dl * CH + ch], 1);
        // compact 4B record: src (17b) | sign-stripped bf16(|w|) (15b)
        edges[pos] = (r.x & 0x1FFFFu) | ((uint_t)f2b(__uint_as_float(r.y)) << 17);
    }
}

// ---------------- weight transpose + bf16 convert (once per call, tiny) -------
__global__ __launch_bounds__(256) void gcn_wt(
    const float* __restrict__ W1, const float* __restrict__ W2,
    const float* __restrict__ W3,
    ushort_t* __restrict__ Wt1, ushort_t* __restrict__ Wt2,
    ushort_t* __restrict__ Wt3)
{
    int i = blockIdx.x * 256 + threadIdx.x;
    if (i < 96 * 128) {                       // layer 1: Wt1[96][128]
        int n = i / 128, k = i % 128;
        Wt1[i] = f2b(W1[k * 96 + n]);
    }
    if (i < 96 * 96) {                        // layer 2: Wt2[96][96]
        int n = i / 96, k = i % 96;
        Wt2[i] = f2b(W2[k * 96 + n]);
    }
    if (i < 32 * 96) {                        // layer 3: Wt3[32][96], pad rows 30,31
        int n = i / 96, k = i % 96;
        Wt3[i] = f2b((n < 30) ? W3[k * 30 + n] : 0.0f);
    }
}

// ---------------- MFMA GEMM: Y[row,:] = dis[row] * (X[row,:] @ W) ------------
template<int K, int FOUT, int NTR, int FOUTP, bool XF32>
__global__ __launch_bounds__(256) void gcn_gemm_mfma(
    const void* __restrict__ Xv, const ushort_t* __restrict__ Wt,
    const float* __restrict__ dis, ushort_t* __restrict__ Y, int N)
{
    constexpr int KS = K + 8;
    constexpr int KT = K / 32;
    constexpr int NT = NTR / 16;
    __shared__ ushort_t xs[64 * KS];
    __shared__ ushort_t ws[NTR * KS];

    int t = threadIdx.x;
    int mbase = blockIdx.x * 64;

    {
        constexpr int TOT = NTR * (K / 8);
        const uint4* wg = (const uint4*)Wt;
        for (int i = t; i < TOT; i += 256) {
            int r = i / (K / 8), c8 = i % (K / 8);
            *(uint4*)(ws + r * KS + c8 * 8) = wg[i];
        }
    }
    if (XF32) {
        const float* X = (const float*)Xv;
        constexpr int TOT = 64 * (K / 4);
        for (int i = t; i < TOT; i += 256) {
            int row = i / (K / 4), c4 = i % (K / 4);
            int rg = mbase + row; if (rg >= N) rg = N - 1;
            float4 v = *(const float4*)(X + (size_t)rg * K + c4 * 4);
            uint2 pv;
            pv.x = (uint_t)f2b(v.x) | ((uint_t)f2b(v.y) << 16);
            pv.y = (uint_t)f2b(v.z) | ((uint_t)f2b(v.w) << 16);
            *(uint2*)(xs + row * KS + c4 * 4) = pv;
        }
    } else {
        const ushort_t* X = (const ushort_t*)Xv;
        constexpr int TOT = 64 * (K / 8);
        for (int i = t; i < TOT; i += 256) {
            int row = i / (K / 8), c8 = i % (K / 8);
            int rg = mbase + row; if (rg >= N) rg = N - 1;
            *(uint4*)(xs + row * KS + c8 * 8) = *(const uint4*)(X + (size_t)rg * K + c8 * 8);
        }
    }
    __syncthreads();

    int wave = t >> 6;
    int lane = t & 63;
    int l15 = lane & 15, quad = lane >> 4;

    bf16x8 af[KT];
    #pragma unroll
    for (int kt = 0; kt < KT; kt++)
        af[kt] = *(const bf16x8*)(xs + (wave * 16 + l15) * KS + kt * 32 + quad * 8);

    floatx4 acc[NT];
    #pragma unroll
    for (int nt = 0; nt < NT; nt++) acc[nt] = (floatx4){0.f, 0.f, 0.f, 0.f};

    #pragma unroll
    for (int nt = 0; nt < NT; nt++) {
        #pragma unroll
        for (int kt = 0; kt < KT; kt++) {
            bf16x8 bfr = *(const bf16x8*)(ws + (nt * 16 + l15) * KS + kt * 32 + quad * 8);
            acc[nt] = __builtin_amdgcn_mfma_f32_16x16x32_bf16(af[kt], bfr, acc[nt], 0, 0, 0);
        }
    }

    float dsc[4];
    #pragma unroll
    for (int r = 0; r < 4; r++) {
        int row = mbase + wave * 16 + quad * 4 + r;
        dsc[r] = (row < N) ? dis[row] : 0.0f;
    }
    #pragma unroll
    for (int nt = 0; nt < NT; nt++) {
        int col = nt * 16 + l15;
        #pragma unroll
        for (int r = 0; r < 4; r++) {
            int row = mbase + wave * 16 + quad * 4 + r;
            if (row < N) {
                float v = (col < FOUT) ? acc[nt][r] * dsc[r] : 0.0f;
                Y[(size_t)row * FOUTP + col] = f2b(v);
            }
        }
    }
}

// ---------------- aggregation: node-parallel gather MLP -----------------------
// R3 evidence: BW-saturated on the gather path (occupancy 66%->46% with zero
// BW change; in-flight >> BW*latency). Structure kept; L2 hit rate is the only
// lever (CH=16 chunk sync, done in bsort).
// XWS = dis-scaled xw. H[n] = relu(b + dis[n]*(sum_e w*XWS[src] + XWS[n])).
template<int FOUT, int FOUTP, int LPN, int BLK>
__global__ __launch_bounds__(BLK) void gcn_agg(
    const ushort_t* __restrict__ XWS, const int* __restrict__ rp,
    const uint_t* __restrict__ edges,
    const float* __restrict__ dis, const float* __restrict__ bias,
    ushort_t* __restrict__ H, int N)
{
    constexpr int NC = FOUTP / 8;           // uint4 per row (== LPN)
    int n = blockIdx.x * (BLK / LPN) + threadIdx.x / LPN;
    int c = threadIdx.x % LPN;
    if (n >= N) return;
    const uint4* xwc = (const uint4*)XWS;

    int beg = rp[n], end = rp[n + 1];
    float a[8];
    #pragma unroll
    for (int j = 0; j < 8; j++) a[j] = 0.0f;

    int e = beg;
    for (; e + 8 <= end; e += 8) {
        uint_t r0 = __builtin_nontemporal_load(edges + e);
        uint_t r1 = __builtin_nontemporal_load(edges + e + 1);
        uint_t r2 = __builtin_nontemporal_load(edges + e + 2);
        uint_t r3 = __builtin_nontemporal_load(edges + e + 3);
        uint_t r4 = __builtin_nontemporal_load(edges + e + 4);
        uint_t r5 = __builtin_nontemporal_load(edges + e + 5);
        uint_t r6 = __builtin_nontemporal_load(edges + e + 6);
        uint_t r7 = __builtin_nontemporal_load(edges + e + 7);
        uint4 v0 = xwc[(size_t)(r0 & 0x1FFFFu) * NC + c];
        uint4 v1 = xwc[(size_t)(r1 & 0x1FFFFu) * NC + c];
        uint4 v2 = xwc[(size_t)(r2 & 0x1FFFFu) * NC + c];
        uint4 v3 = xwc[(size_t)(r3 & 0x1FFFFu) * NC + c];
        uint4 v4 = xwc[(size_t)(r4 & 0x1FFFFu) * NC + c];
        uint4 v5 = xwc[(size_t)(r5 & 0x1FFFFu) * NC + c];
        uint4 v6 = xwc[(size_t)(r6 & 0x1FFFFu) * NC + c];
        uint4 v7 = xwc[(size_t)(r7 & 0x1FFFFu) * NC + c];
        __builtin_amdgcn_sched_barrier(0);   // keep all 8 gathers in flight
        fma8(a, v0, wdec(r0));
        fma8(a, v1, wdec(r1));
        fma8(a, v2, wdec(r2));
        fma8(a, v3, wdec(r3));
        fma8(a, v4, wdec(r4));
        fma8(a, v5, wdec(r5));
        fma8(a, v6, wdec(r6));
        fma8(a, v7, wdec(r7));
    }
    for (; e + 4 <= end; e += 4) {
        uint_t r0 = __builtin_nontemporal_load(edges + e);
        uint_t r1 = __builtin_nontemporal_load(edges + e + 1);
        uint_t r2 = __builtin_nontemporal_load(edges + e + 2);
        uint_t r3 = __builtin_nontemporal_load(edges + e + 3);
        uint4 v0 = xwc[(size_t)(r0 & 0x1FFFFu) * NC + c];
        uint4 v1 = xwc[(size_t)(r1 & 0x1FFFFu) * NC + c];
        uint4 v2 = xwc[(size_t)(r2 & 0x1FFFFu) * NC + c];
        uint4 v3 = xwc[(size_t)(r3 & 0x1FFFFu) * NC + c];
        __builtin_amdgcn_sched_barrier(0);
        fma8(a, v0, wdec(r0));
        fma8(a, v1, wdec(r1));
        fma8(a, v2, wdec(r2));
        fma8(a, v3, wdec(r3));
    }
    for (; e < end; e++) {
        uint_t r0 = __builtin_nontemporal_load(edges + e);
        uint4 v0 = xwc[(size_t)(r0 & 0x1FFFFu) * NC + c];
        fma8(a, v0, wdec(r0));
    }

    uint4 sv = xwc[(size_t)n * NC + c];
    fma8(a, sv, 1.0f);                 // + XWS[n]
    float d = dis[n];
    int f0 = c * 8;
    uint_t o[4];
    #pragma unroll
    for (int p = 0; p < 4; p++) {
        float rA = (f0 + 2 * p     < FOUT) ? fmaxf(a[2 * p]     * d + bias[f0 + 2 * p],     0.f) : 0.f;
        float rB = (f0 + 2 * p + 1 < FOUT) ? fmaxf(a[2 * p + 1] * d + bias[f0 + 2 * p + 1], 0.f) : 0.f;
        o[p] = (uint_t)f2b(rA) | ((uint_t)f2b(rB) << 16);
    }
    uint4 ov = {o[0], o[1], o[2], o[3]};
    *((uint4*)H + (size_t)n * NC + c) = ov;
}

// ---------------- mean-pool per graph + final linear + softmax ----------------
__global__ __launch_bounds__(256) void gcn_pool(
    const ushort_t* __restrict__ H, const int* __restrict__ batch,
    const float* __restrict__ Wf, const float* __restrict__ bf_,
    float* __restrict__ out, int N)
{
    __shared__ float pool[32];
    int g = blockIdx.x;
    int t = threadIdx.x;

    int lo = 0, hi = N;
    while (lo < hi) { int mid = (lo + hi) >> 1; if (batch[mid] < g) lo = mid + 1; else hi = mid; }
    int start = lo;
    lo = 0; hi = N;
    while (lo < hi) { int mid = (lo + hi) >> 1; if (batch[mid] < g + 1) lo = mid + 1; else hi = mid; }
    int end = lo;

    float acc[32];
    #pragma unroll
    for (int f = 0; f < 32; f++) acc[f] = 0.0f;
    for (int i = start + t; i < end; i += 256) {
        const uint2* hr = (const uint2*)H + (size_t)i * 8;
        #pragma unroll
        for (int q = 0; q < 8; q++) {
            uint2 v = hr[q];
            acc[4 * q + 0] += b2f(v.x & 0xffffu);
            acc[4 * q + 1] += b2f(v.x >> 16);
            acc[4 * q + 2] += b2f(v.y & 0xffffu);
            acc[4 * q + 3] += b2f(v.y >> 16);
        }
    }
    #pragma unroll
    for (int f = 0; f < 32; f++) {
        float v = acc[f];
        v += __shfl_down(v, 32, 64);
        v += __shfl_down(v, 16, 64);
        v += __shfl_down(v, 8, 64);
        v += __shfl_down(v, 4, 64);
        v += __shfl_down(v, 2, 64);
        v += __shfl_down(v, 1, 64);
        acc[f] = v;
    }
    if (t < 32) pool[t] = 0.0f;
    __syncthreads();
    if ((t & 63) == 0) {
        #pragma unroll
        for (int f = 0; f < 30; f++) atomicAdd(&pool[f], acc[f]);
    }
    __syncthreads();
    if (t == 0) {
        float inv = 1.0f / fmaxf((float)(end - start), 1.0f);
        float lg[10];
        #pragma unroll
        for (int j = 0; j < 10; j++) lg[j] = bf_[j];
        for (int f = 0; f < 30; f++) {
            float p = pool[f] * inv;
            #pragma unroll
            for (int j = 0; j < 10; j++) lg[j] += p * Wf[f * 10 + j];
        }
        float m = lg[0];
        #pragma unroll
        for (int j = 1; j < 10; j++) m = fmaxf(m, lg[j]);
        float s = 0.f;
        #pragma unroll
        for (int j = 0; j < 10; j++) { lg[j] = __expf(lg[j] - m); s += lg[j]; }
        float is = 1.0f / s;
        #pragma unroll
        for (int j = 0; j < 10; j++) out[g * 10 + j] = lg[j] * is;
    }
}

extern "C" void kernel_launch(void* const* d_in, const int* in_sizes, int n_in,
                              void* d_out, int out_size, void* d_ws, size_t ws_size,
                              hipStream_t stream) {
    (void)n_in; (void)out_size; (void)ws_size;
    const float* x   = (const float*)d_in[0];
    const int*   ei  = (const int*)d_in[1];
    const float* ew  = (const float*)d_in[2];
    const int*   bat = (const int*)d_in[3];
    const float* W1  = (const float*)d_in[4];
    const float* b1  = (const float*)d_in[5];
    const float* W2  = (const float*)d_in[6];
    const float* b2  = (const float*)d_in[7];
    const float* W3  = (const float*)d_in[8];
    const float* b3  = (const float*)d_in[9];
    const float* Wf  = (const float*)d_in[10];
    const float* bf_ = (const float*)d_in[11];
    float* out = (float*)d_out;

    const int N = in_sizes[3];       // 100000
    const int E = in_sizes[2];       // 3200000
    const int NB = (N + NPB - 1) / NPB;   // 782
    int gB = (E + EPB - 1) / EPB;         // 196
    gB = (gB + 3) & ~3;                   // pad rows to multiple of 4 for uint4 rebase

    char* wsb = (char*)d_ws;
    size_t o = 0;
    auto take = [&](size_t bytes) -> char* {
        char* p = wsb + o;
        o += (bytes + 255) & ~(size_t)255;
        return p;
    };
    int*      bkt_cnt    = (int*)take(NBMAX * 4);             // zeroed each call
    int*      bkt_base   = (int*)take((NBMAX + 1) * 4);
    int*      hist_t     = (int*)take((size_t)NBMAX * gB * 4);  // [bucket][block]
    int*      rp         = (int*)take((size_t)(N + 1) * 4);
    float*    dis        = (float*)take((size_t)N * 4);
    uint2*    stage      = (uint2*)take((size_t)E * 8);       // dead after bsort; xw aliases it
    uint_t*   edges      = (uint_t*)take((size_t)E * 4);      // compact 4B records
    ushort_t* h          = (ushort_t*)take((size_t)N * 96 * 2);
    ushort_t* Wt1        = (ushort_t*)take(96 * 128 * 2);
    ushort_t* Wt2        = (ushort_t*)take(96 * 96 * 2);
    ushort_t* Wt3        = (ushort_t*)take(32 * 96 * 2);
    ushort_t* xw         = (ushort_t*)stage;                  // alias (E*8 >= N*96*2)

    const int gBr = (E + EPB - 1) / EPB;  // real number of hist/scatter blocks
    const int gM = (N + 63) / 64;

    hipMemsetAsync(bkt_cnt, 0, NBMAX * 4, stream);
    // zero the padded tail rows of hist_t so rebase scan stays correct
    if (gB != gBr) {
        // pad columns [gBr, gB) for every bucket: memset whole table is cheap (0.8MB)
        hipMemsetAsync(hist_t, 0, (size_t)NBMAX * gB * 4, stream);
    }

    // CSR build: hist (+cols) -> scan -> rebase -> deterministic scatter -> sort
    gcn_bhist<<<gBr, 1024, 0, stream>>>(ei, bkt_cnt, hist_t, E, NB, gB);
    gcn_wt<<<48, 256, 0, stream>>>(W1, W2, W3, Wt1, Wt2, Wt3);
    gcn_bscan<<<1, 256, 0, stream>>>(bkt_cnt, bkt_base, rp, NB, N, E);
    gcn_brebase<<<(NB + 255) / 256, 256, 0, stream>>>(hist_t, bkt_base, NB, gB);
    gcn_bscatter<<<gBr, 1024, 0, stream>>>(ei, ew, hist_t, stage, E, NB, gB);
    gcn_bsort<<<NB, 256, 0, stream>>>(stage, edges, bkt_base, rp, dis, N);

    // agg grids: oversubscribed (max wave parallelism)
    const int gA96 = (N + 15) / 16;    // 6250 blocks x 3 waves
    const int gA32 = (N + 63) / 64;    // 1563 blocks x 4 waves

    // layer 1: x[.,128](fp32) -> xws[.,96](bf16, dis-scaled) -> h[.,96](bf16)
    gcn_gemm_mfma<128, 96, 96, 96, true><<<gM, 256, 0, stream>>>(x, Wt1, dis, xw, N);
    gcn_agg<96, 96, 12, 192><<<gA96, 192, 0, stream>>>(xw, rp, edges, dis, b1, h, N);

    // layer 2
    gcn_gemm_mfma<96, 96, 96, 96, false><<<gM, 256, 0, stream>>>(h, Wt2, dis, xw, N);
    gcn_agg<96, 96, 12, 192><<<gA96, 192, 0, stream>>>(xw, rp, edges, dis, b2, h, N);

    // layer 3 (FOUT=30 padded to 32)
    gcn_gemm_mfma<96, 30, 32, 32, false><<<gM, 256, 0, stream>>>(h, Wt3, dis, xw, N);
    gcn_agg<30, 32, 4, 256><<<gA32, 256, 0, stream>>>(xw, rp, edges, dis, b3, h, N);

    // mean pool + classifier + softmax
    gcn_pool<<<256, 256, 0, stream>>>(h, bat, Wf, bf_, out, N);
}